// Round 21
// baseline (292.072 us; speedup 1.0000x reference)
//
#include <hip/hip_runtime.h>
#include <hip/hip_bf16.h>

// Temporal_Aggregation — MFMA bf16, fp32 I/O (MI355X gfx950). Round 30.
// (= Round-28/29 LDS-free kernel, unmeasured after repeated broker
//  timeouts; resubmitted unchanged — never mutate an unmeasured experiment.)
//
// Five falsified theories (spill r12, occupancy r11, read-MLP r14, write-path
// r17, barriers r18). Surviving account: per-wave issue work ~0.5us but wall
// ~7us — waves wait on the A-path dependency chain global->cvt->ds_write->
// lgkm->ds_read->MFMA, with loads serialized by the tiny (40-48) VGPR
// allocations the staging structure induces.
//
// NO LDS AT ALL. A lane's A-fragment for (mt,ks) is 8 consecutive floats in
// global memory: value[base + rr*1536 + t_eff*64 + (ks&1)*32 + quad*8 + e],
// t_eff = clamp(s + (ks>>1) - 1). Load 2xf4 per fragment directly, cvt
// in-register, MFMA. 3x tap overlap + 4x cross-wave reuse served by L1
// (12 KB block working set). 36 independent f4 loads per wave,
// launch_bounds(256,3) (~168 VGPR cap) -> deep MLP instead of 2-3-deep
// register-starved batches. Edge taps: clamped address + zero-select
// (t=-1 only at s==0; t=24 only at s==23).
// Epilogue: r27 3-mt shuffle band-sum (hardware-validated, r18 passed).
//
// Folded math (validated rounds 4-8):
//   Wbig[o][j=k*64+i] = sum_c Wlin[o][c]*Wconv[c][i][0][k]   (bf16 in ws)
//   z[t][o]  = sum_j Vp[t+(j>>6)][j&63] * Wbig[o][j]
//   out[t][o] = relu( z[t-1]+z[t]+z[t+1] (clipped) + m_t*biasC[o] + blin[o] )

typedef __attribute__((ext_vector_type(8))) short short8;
typedef __attribute__((ext_vector_type(8))) unsigned short ushort8;
typedef __attribute__((ext_vector_type(8))) __bf16 bf16x8;
typedef __attribute__((ext_vector_type(4))) float f4;

#define ROWS_PB 2                      // rows per block (4 waves share, L1)

__device__ __forceinline__ unsigned short f2bfu(float f) {
    return __bfloat16_as_ushort(__float2bfloat16(f));
}

// ---- Kernel 1: fold conv+linear weights -------------------------------------
// ws bytes: [0,24576) Wbig bf16[64][192]; [24576,24832) biasC f32[64];
//           [24832,25088) blinF f32[64]
__global__ void prep_kernel(const float* __restrict__ Wconv,
                            const float* __restrict__ bconv,
                            const float* __restrict__ Wlin,
                            const float* __restrict__ blin,
                            __hip_bfloat16* __restrict__ wbig,
                            float* __restrict__ biasC,
                            float* __restrict__ blinF) {
    __shared__ float Wl[4096];
    const int tid = threadIdx.x;
    for (int c = tid; c < 4096; c += 256) Wl[c] = Wlin[c];
    __syncthreads();
    int idx = blockIdx.x * 256 + tid;
    if (idx < 64 * 192) {
        int o = idx / 192;
        int j = idx - o * 192;
        int k = j >> 6;
        int i = j & 63;
        float acc = 0.0f;
        for (int c = 0; c < 64; ++c)
            acc += Wl[o * 64 + c] * Wconv[c * 192 + i * 3 + k];
        wbig[o * 192 + j] = __float2bfloat16(acc);
    } else if (idx < 64 * 192 + 64) {
        int o = idx - 64 * 192;
        float acc = 0.0f;
        for (int c = 0; c < 64; ++c)
            acc += Wl[o * 64 + c] * bconv[c];
        biasC[o] = acc;
    } else if (idx < 64 * 192 + 128) {
        int o = idx - (64 * 192 + 64);
        blinF[o] = blin[o];
    }
}

// ---- Kernel 2: LDS-free fused conv-GEMM + band sum + bias + relu ------------
__global__ __launch_bounds__(256, 3) void fused_kernel(
    const float* __restrict__ value,
    const __hip_bfloat16* __restrict__ wbig,
    const float* __restrict__ biasC,
    const float* __restrict__ blinF,
    float* __restrict__ out) {
    const int tid = threadIdx.x;
    const int wave = tid >> 6;            // o-tile index (16 columns)
    const int lane = tid & 63;
    const int lane15 = lane & 15;
    const int quad = lane >> 4;
    const long base_row = (long)blockIdx.x * ROWS_PB;

    // ---- B fragments for this wave's o-tile (L2-hot after block 0) ----
    const short* wsrc = (const short*)wbig;
    bf16x8 breg[6];
    #pragma unroll
    for (int ks = 0; ks < 6; ++ks)
        breg[ks] = __builtin_bit_cast(bf16x8,
            *(const short8*)(wsrc + (wave * 16 + lane15) * 192
                             + ks * 32 + quad * 8));

    const int o = wave * 16 + lane15;
    const float bc = biasC[o];
    const float bl = blinF[o];

    // per-lane column base: + quad*8 floats (i-offset within tap row)
    const float* vb = value + base_row * 1536 + quad * 8;

    f4 acc[3];
    #pragma unroll
    for (int mt = 0; mt < 3; ++mt) {
        f4 zz = {0.f, 0.f, 0.f, 0.f};
        acc[mt] = zz;
    }

    // ---- K-loop: A-fragments straight from global (L1-served), no LDS ----
    #pragma unroll
    for (int mt = 0; mt < 3; ++mt) {
        const int m = mt * 16 + lane15;        // GEMM row 0..47
        const int rr = (m >= 24) ? 1 : 0;      // row-in-block
        const int s = m - rr * 24;             // t = 0..23
        const bool lo = (s == 0);              // t-1 out of range
        const bool hi = (s == 23);             // t+1 out of range
        const float* rbase = vb + rr * 1536;
        const float* r0 = rbase + (lo ? 0 : (s - 1)) * 64;   // tap kk=0
        const float* r1 = rbase + s * 64;                    // tap kk=1
        const float* r2 = rbase + (hi ? 23 : (s + 1)) * 64;  // tap kk=2

        // 12 independent f4 loads (all issued before first use)
        f4 p[12];
        p[0]  = *(const f4*)(r0);       p[1]  = *(const f4*)(r0 + 4);
        p[2]  = *(const f4*)(r0 + 32);  p[3]  = *(const f4*)(r0 + 36);
        p[4]  = *(const f4*)(r1);       p[5]  = *(const f4*)(r1 + 4);
        p[6]  = *(const f4*)(r1 + 32);  p[7]  = *(const f4*)(r1 + 36);
        p[8]  = *(const f4*)(r2);       p[9]  = *(const f4*)(r2 + 4);
        p[10] = *(const f4*)(r2 + 32);  p[11] = *(const f4*)(r2 + 36);

        // zero the out-of-range taps (clamped addresses stayed in-bounds)
        f4 zf = {0.f, 0.f, 0.f, 0.f};
        if (lo) { p[0] = zf; p[1] = zf; p[2] = zf; p[3] = zf; }
        if (hi) { p[8] = zf; p[9] = zf; p[10] = zf; p[11] = zf; }

        // pack + MFMA: ks -> (tap kk=ks>>1, i-half ks&1) -> p[2ks], p[2ks+1]
        #pragma unroll
        for (int ks = 0; ks < 6; ++ks) {
            f4 plo = p[ks * 2];
            f4 phi = p[ks * 2 + 1];
            ushort8 u;
            u[0] = f2bfu(plo.x); u[1] = f2bfu(plo.y);
            u[2] = f2bfu(plo.z); u[3] = f2bfu(plo.w);
            u[4] = f2bfu(phi.x); u[5] = f2bfu(phi.y);
            u[6] = f2bfu(phi.z); u[7] = f2bfu(phi.w);
            acc[mt] = __builtin_amdgcn_mfma_f32_16x16x32_bf16(
                __builtin_bit_cast(bf16x8, u), breg[ks], acc[mt], 0, 0, 0);
        }
    }

    // ---- epilogue: wave-local shuffle band sum, bias, relu, store ----
    // C/D layout: col = lane&15, row16 = quad*4 + i  [m89]
    // m = mt*16 + quad*4 + i (0..47); out off = blockIdx*3072 + m*64 + o.
    // t0 at m=0 (mt0,q0) and m=24 (mt1,q2); t23 at m=23 (mt1,q1) and
    // m=47 (mt2,q3); all at i=0 / i=3 only (m === i mod 4).
    const float b3 = 3.0f * bc + bl;
    const float b2 = 2.0f * bc + bl;
    const int srcP = (lane + 48) & 63;    // receive from quad-1
    const int srcN = (lane + 16) & 63;    // receive from quad+1
    float* pbase = out + (long)blockIdx.x * 3072 + quad * 256 + o;
    #pragma unroll
    for (int mt = 0; mt < 3; ++mt) {
        const int mtp = (mt > 0) ? mt - 1 : 0;
        const int mtn = (mt < 2) ? mt + 1 : 2;
        float sendP = (quad == 3) ? acc[mtp][3] : acc[mt][3];
        float sendN = (quad == 0) ? acc[mtn][0] : acc[mt][0];
        float prev0 = __shfl(sendP, srcP, 64);
        float next3 = __shfl(sendN, srcN, 64);
        const bool t0  = (mt == 0) ? (quad == 0)
                       : ((mt == 1) ? (quad == 2) : false);
        const bool t23 = (mt == 2) ? (quad == 3)
                       : ((mt == 1) ? (quad == 1) : false);
        float s0 = acc[mt][0] + acc[mt][1] + (t0  ? b2 : (prev0 + b3));
        float s1 = acc[mt][0] + acc[mt][1] + acc[mt][2] + b3;
        float s2 = acc[mt][1] + acc[mt][2] + acc[mt][3] + b3;
        float s3 = acc[mt][2] + acc[mt][3] + (t23 ? b2 : (next3 + b3));
        float* p = pbase + mt * 1024;     // mt*16*64, compile-time
        p[0]   = fmaxf(s0, 0.0f);
        p[64]  = fmaxf(s1, 0.0f);
        p[128] = fmaxf(s2, 0.0f);
        p[192] = fmaxf(s3, 0.0f);
    }
}

extern "C" void kernel_launch(void* const* d_in, const int* in_sizes, int n_in,
                              void* d_out, int out_size, void* d_ws, size_t ws_size,
                              hipStream_t stream) {
    const float* value = (const float*)d_in[0];
    const float* Wconv = (const float*)d_in[1];
    const float* bconv = (const float*)d_in[2];
    const float* Wlin  = (const float*)d_in[3];
    const float* blin  = (const float*)d_in[4];
    float* out = (float*)d_out;

    __hip_bfloat16* wbig = (__hip_bfloat16*)d_ws;
    float* biasC = (float*)((char*)d_ws + 24576);
    float* blinF = (float*)((char*)d_ws + 24832);

    prep_kernel<<<49, 256, 0, stream>>>(Wconv, bconv, Wlin, blin, wbig, biasC, blinF);
    // 16384 rows / 2 per block = 8192 blocks, zero LDS, zero barriers
    fused_kernel<<<8192, 256, 0, stream>>>(value, wbig, biasC, blinF, out);
}